// Round 2
// baseline (3021.359 us; speedup 1.0000x reference)
//
#include <hip/hip_runtime.h>

#define N_NODES   100000
#define N_EDGES   3200000
#define F_INP     128
#define HID       64
#define N_GRAPHS  512
#define N_CLASSES 2
#define NB        782                      // ceil(N/128) buckets of 128 target nodes
#define SCAT_BLOCKS 256
#define CHUNK     (N_EDGES / SCAT_BLOCKS)  // 12500, exact

// ---------- pass 1: global bucket histogram (LDS-aggregated) ----------
__global__ __launch_bounds__(256) void hist_kernel(const int* __restrict__ ei,
                                                   int* __restrict__ bcnt) {
    __shared__ int hist[NB];
    for (int i = threadIdx.x; i < NB; i += 256) hist[i] = 0;
    __syncthreads();
    const int e0 = blockIdx.x * CHUNK, e1 = e0 + CHUNK;
    for (int e = e0 + threadIdx.x; e < e1; e += 256)
        atomicAdd(&hist[ei[N_EDGES + e] >> 7], 1);
    __syncthreads();
    for (int i = threadIdx.x; i < NB; i += 256)
        if (hist[i]) atomicAdd(&bcnt[i], hist[i]);
}

// ---------- pass 2: exclusive scan over 782 buckets (one block) ----------
__global__ __launch_bounds__(1024) void scan_kernel(const int* __restrict__ bcnt,
                                                    int* __restrict__ boff,
                                                    int* __restrict__ gcur) {
    __shared__ int s[1024];
    const int tid = threadIdx.x;
    const int v = (tid < NB) ? bcnt[tid] : 0;
    s[tid] = v;
    __syncthreads();
    for (int d = 1; d < 1024; d <<= 1) {
        int t = (tid >= d) ? s[tid - d] : 0;
        __syncthreads();
        s[tid] += t;
        __syncthreads();
    }
    if (tid <= NB) {
        int ex = s[tid] - v;               // exclusive; tid==NB -> total == N_EDGES
        boff[tid] = ex;
        if (tid < NB) gcur[tid] = ex;
    }
}

// ---------- pass 3: localized scatter into bucket-sorted packed pairs ----------
// pairs[e] = r | ((c & 127) << 17);  r < 2^17, local target index in high bits
__global__ __launch_bounds__(256) void scatter_kernel(const int* __restrict__ ei,
                                                      int* __restrict__ gcur,
                                                      int* __restrict__ pairs) {
    __shared__ int hist[NB];
    __shared__ int lbase[NB];
    __shared__ int lcur[NB];
    for (int i = threadIdx.x; i < NB; i += 256) { hist[i] = 0; lcur[i] = 0; }
    __syncthreads();
    const int e0 = blockIdx.x * CHUNK, e1 = e0 + CHUNK;
    for (int e = e0 + threadIdx.x; e < e1; e += 256)
        atomicAdd(&hist[ei[N_EDGES + e] >> 7], 1);
    __syncthreads();
    for (int i = threadIdx.x; i < NB; i += 256)
        lbase[i] = hist[i] ? atomicAdd(&gcur[i], hist[i]) : 0;
    __syncthreads();
    for (int e = e0 + threadIdx.x; e < e1; e += 256) {
        int c = ei[N_EDGES + e];
        int r = ei[e];
        int b = c >> 7;
        int off = atomicAdd(&lcur[b], 1);
        pairs[lbase[b] + off] = r | ((c & 127) << 17);
    }
}

// ---------- dis = rsqrt(in_degree + 1), from sorted pairs (LDS histogram) ----------
__global__ __launch_bounds__(256) void dis_kernel(const int* __restrict__ pairs,
                                                  const int* __restrict__ boff,
                                                  float* __restrict__ dis) {
    __shared__ int cnt[128];
    if (threadIdx.x < 128) cnt[threadIdx.x] = 0;
    __syncthreads();
    const int b = blockIdx.x;
    const int beg = boff[b], end = boff[b + 1];
    for (int e = beg + threadIdx.x; e < end; e += 256)
        atomicAdd(&cnt[pairs[e] >> 17], 1);
    __syncthreads();
    const int n = (b << 7) + threadIdx.x;
    if (threadIdx.x < 128 && n < N_NODES)
        dis[n] = rsqrtf((float)cnt[threadIdx.x] + 1.0f);
}

// ---------- per-graph node counts: batch is sorted -> binary search ----------
__global__ void counts_kernel(const int* __restrict__ batch, int* __restrict__ counts) {
    const int g = blockIdx.x * blockDim.x + threadIdx.x;
    if (g >= N_GRAPHS) return;
    int lo = 0, hi = N_NODES;
    while (lo < hi) { int m = (lo + hi) >> 1; if (batch[m] < g) lo = m + 1; else hi = m; }
    const int l0 = lo;
    lo = 0; hi = N_NODES;
    while (lo < hi) { int m = (lo + hi) >> 1; if (batch[m] < g + 1) lo = m + 1; else hi = m; }
    counts[g] = lo - l0;
}

// ---------- mm1: p = dis * (x @ W1)   [N,128]@[128,64] ----------
__global__ __launch_bounds__(256) void mm1_kernel(const float* __restrict__ x,
                                                  const float* __restrict__ W1,
                                                  const float* __restrict__ dis,
                                                  float* __restrict__ p) {
    const int lane = threadIdx.x & 63;
    const int wid  = threadIdx.x >> 6;
    float4 w[32];                      // column `lane` of W1 in regs
#pragma unroll
    for (int kk = 0; kk < 32; ++kk)
        w[kk] = make_float4(W1[(4 * kk + 0) * HID + lane], W1[(4 * kk + 1) * HID + lane],
                            W1[(4 * kk + 2) * HID + lane], W1[(4 * kk + 3) * HID + lane]);
    const int gw = blockIdx.x * 4 + wid;
    const int tw = gridDim.x * 4;
    for (int base = gw * 2; base < N_NODES; base += tw * 2) {
        const int r0 = base, r1 = base + 1;
        const float4* x0 = (const float4*)(x + (size_t)r0 * F_INP);
        const float4* x1 = (const float4*)(x + (size_t)r1 * F_INP);
        float a0 = 0.f, a1 = 0.f;
#pragma unroll
        for (int kk = 0; kk < 32; ++kk) {
            float4 v0 = x0[kk];
            float4 v1 = x1[kk];
            a0 += v0.x * w[kk].x + v0.y * w[kk].y + v0.z * w[kk].z + v0.w * w[kk].w;
            a1 += v1.x * w[kk].x + v1.y * w[kk].y + v1.z * w[kk].z + v1.w * w[kk].w;
        }
        p[(size_t)r0 * HID + lane] = dis[r0] * a0;
        p[(size_t)r1 * HID + lane] = dis[r1] * a1;
    }
}

// ---------- mm2: p = dis * (h @ W2)   [N,64]@[64,64] ----------
__global__ __launch_bounds__(256) void mm2_kernel(const float* __restrict__ h,
                                                  const float* __restrict__ W2,
                                                  const float* __restrict__ dis,
                                                  float* __restrict__ p) {
    const int lane = threadIdx.x & 63;
    const int wid  = threadIdx.x >> 6;
    float4 w[16];
#pragma unroll
    for (int kk = 0; kk < 16; ++kk)
        w[kk] = make_float4(W2[(4 * kk + 0) * HID + lane], W2[(4 * kk + 1) * HID + lane],
                            W2[(4 * kk + 2) * HID + lane], W2[(4 * kk + 3) * HID + lane]);
    const int gw = blockIdx.x * 4 + wid;
    const int tw = gridDim.x * 4;
    for (int base = gw * 2; base < N_NODES; base += tw * 2) {
        const int r0 = base, r1 = base + 1;
        const float4* h0 = (const float4*)(h + (size_t)r0 * HID);
        const float4* h1 = (const float4*)(h + (size_t)r1 * HID);
        float a0 = 0.f, a1 = 0.f;
#pragma unroll
        for (int kk = 0; kk < 16; ++kk) {
            float4 v0 = h0[kk];
            float4 v1 = h1[kk];
            a0 += v0.x * w[kk].x + v0.y * w[kk].y + v0.z * w[kk].z + v0.w * w[kk].w;
            a1 += v1.x * w[kk].x + v1.y * w[kk].y + v1.z * w[kk].z + v1.w * w[kk].w;
        }
        p[(size_t)r0 * HID + lane] = dis[r0] * a0;
        p[(size_t)r1 * HID + lane] = dis[r1] * a1;
    }
}

// ---------- gather layer 1: LDS 128x64 accumulator per bucket ----------
__global__ __launch_bounds__(256) void gather1_kernel(const float* __restrict__ p,
                                                      const int* __restrict__ pairs,
                                                      const int* __restrict__ boff,
                                                      const float* __restrict__ dis,
                                                      const float* __restrict__ b1,
                                                      float* __restrict__ h) {
    __shared__ float acc[128 * HID];
    const int lane = threadIdx.x & 63;
    const int wid  = threadIdx.x >> 6;
    const int b = blockIdx.x;
    const int n0 = b << 7;
    const int nodes = min(128, N_NODES - n0);
    for (int i = wid; i < nodes; i += 4)                       // self-loop init
        acc[i * HID + lane] = p[(size_t)(n0 + i) * HID + lane];
    __syncthreads();
    const int beg = boff[b], end = boff[b + 1];
    const int chunk = (end - beg + 3) >> 2;                    // contiguous chunk per wave
    int e = beg + wid * chunk;
    const int t = min(end, e + chunk);
    for (; e + 3 < t; e += 4) {
        int v0 = pairs[e], v1 = pairs[e + 1], v2 = pairs[e + 2], v3 = pairs[e + 3];
        float m0 = p[(size_t)(v0 & 131071) * HID + lane];
        float m1 = p[(size_t)(v1 & 131071) * HID + lane];
        float m2 = p[(size_t)(v2 & 131071) * HID + lane];
        float m3 = p[(size_t)(v3 & 131071) * HID + lane];
        atomicAdd(&acc[(v0 >> 17) * HID + lane], m0);
        atomicAdd(&acc[(v1 >> 17) * HID + lane], m1);
        atomicAdd(&acc[(v2 >> 17) * HID + lane], m2);
        atomicAdd(&acc[(v3 >> 17) * HID + lane], m3);
    }
    for (; e < t; ++e) {
        int v = pairs[e];
        atomicAdd(&acc[(v >> 17) * HID + lane], p[(size_t)(v & 131071) * HID + lane]);
    }
    __syncthreads();
    const float bj = b1[lane];
    for (int i = wid; i < nodes; i += 4) {
        int n = n0 + i;
        h[(size_t)n * HID + lane] = fmaxf(dis[n] * acc[i * HID + lane] + bj, 0.f);
    }
}

// ---------- gather layer 2 + fused mean-pool numerator (run-length atomics) ----------
__global__ __launch_bounds__(256) void gather2_kernel(const float* __restrict__ p,
                                                      const int* __restrict__ pairs,
                                                      const int* __restrict__ boff,
                                                      const float* __restrict__ dis,
                                                      const float* __restrict__ b2,
                                                      const int* __restrict__ batch,
                                                      float* __restrict__ sums) {
    __shared__ float acc[128 * HID];
    const int lane = threadIdx.x & 63;
    const int wid  = threadIdx.x >> 6;
    const int b = blockIdx.x;
    const int n0 = b << 7;
    const int nodes = min(128, N_NODES - n0);
    for (int i = wid; i < nodes; i += 4)
        acc[i * HID + lane] = p[(size_t)(n0 + i) * HID + lane];
    __syncthreads();
    const int beg = boff[b], end = boff[b + 1];
    const int chunk = (end - beg + 3) >> 2;
    int e = beg + wid * chunk;
    const int t = min(end, e + chunk);
    for (; e + 3 < t; e += 4) {
        int v0 = pairs[e], v1 = pairs[e + 1], v2 = pairs[e + 2], v3 = pairs[e + 3];
        float m0 = p[(size_t)(v0 & 131071) * HID + lane];
        float m1 = p[(size_t)(v1 & 131071) * HID + lane];
        float m2 = p[(size_t)(v2 & 131071) * HID + lane];
        float m3 = p[(size_t)(v3 & 131071) * HID + lane];
        atomicAdd(&acc[(v0 >> 17) * HID + lane], m0);
        atomicAdd(&acc[(v1 >> 17) * HID + lane], m1);
        atomicAdd(&acc[(v2 >> 17) * HID + lane], m2);
        atomicAdd(&acc[(v3 >> 17) * HID + lane], m3);
    }
    for (; e < t; ++e) {
        int v = pairs[e];
        atomicAdd(&acc[(v >> 17) * HID + lane], p[(size_t)(v & 131071) * HID + lane]);
    }
    __syncthreads();
    // epilogue: relu + pooled partial sums; batch is sorted -> few atomics per wave
    const float bj = b2[lane];
    const int i_beg = wid * 32;
    const int i_end = min(nodes, i_beg + 32);
    float part = 0.f;
    int gc = -1;
    for (int i = i_beg; i < i_end; ++i) {
        int n = n0 + i;
        float v = fmaxf(dis[n] * acc[i * HID + lane] + bj, 0.f);
        int g = batch[n];                  // wave-uniform
        if (g != gc) {
            if (gc >= 0) atomicAdd(&sums[(size_t)gc * HID + lane], part);
            part = 0.f;
            gc = g;
        }
        part += v;
    }
    if (gc >= 0) atomicAdd(&sums[(size_t)gc * HID + lane], part);
}

// ---------- final FC: out[g] = (sums[g]/max(count,1)) @ Wfc + bfc ----------
__global__ void fc_kernel(const float* __restrict__ sums, const int* __restrict__ counts,
                          const float* __restrict__ Wfc, const float* __restrict__ bfc,
                          float* __restrict__ out) {
    const int g = blockIdx.x;
    const int j = threadIdx.x;
    float cnt = fmaxf((float)counts[g], 1.0f);
    float pj = sums[(size_t)g * HID + j] / cnt;
    float a0 = pj * Wfc[j * N_CLASSES + 0];
    float a1 = pj * Wfc[j * N_CLASSES + 1];
    for (int off = 32; off > 0; off >>= 1) {
        a0 += __shfl_down(a0, off, 64);
        a1 += __shfl_down(a1, off, 64);
    }
    if (j == 0) {
        out[g * N_CLASSES + 0] = a0 + bfc[0];
        out[g * N_CLASSES + 1] = a1 + bfc[1];
    }
}

extern "C" void kernel_launch(void* const* d_in, const int* in_sizes, int n_in,
                              void* d_out, int out_size, void* d_ws, size_t ws_size,
                              hipStream_t stream) {
    const float* x     = (const float*)d_in[0];
    const int*   ei    = (const int*)d_in[1];   // [2,E]: row=ei[0:E], col=ei[E:2E]
    const int*   batch = (const int*)d_in[2];
    const float* W1    = (const float*)d_in[3];
    const float* b1    = (const float*)d_in[4];
    const float* W2    = (const float*)d_in[5];
    const float* b2    = (const float*)d_in[6];
    const float* Wfc   = (const float*)d_in[7];
    const float* bfc   = (const float*)d_in[8];
    float* out = (float*)d_out;

    char* ws = (char*)d_ws;
    size_t off = 0;
    auto alloc = [&](size_t bytes) -> void* {
        void* pp = ws + off;
        off += (bytes + 255) & ~(size_t)255;
        return pp;
    };
    int*   bcnt   = (int*)alloc((size_t)NB * 4);
    int*   boff   = (int*)alloc((size_t)(NB + 1) * 4);
    int*   gcur   = (int*)alloc((size_t)NB * 4);
    float* dis    = (float*)alloc((size_t)N_NODES * 4);
    int*   pairs  = (int*)alloc((size_t)N_EDGES * 4);
    float* p      = (float*)alloc((size_t)N_NODES * HID * 4);
    float* h      = (float*)alloc((size_t)N_NODES * HID * 4);
    float* sums   = (float*)alloc((size_t)N_GRAPHS * HID * 4);
    int*   counts = (int*)alloc((size_t)N_GRAPHS * 4);

    hipMemsetAsync(bcnt, 0, (size_t)NB * 4, stream);
    hipMemsetAsync(sums, 0, (size_t)N_GRAPHS * HID * 4, stream);

    hist_kernel<<<SCAT_BLOCKS, 256, 0, stream>>>(ei, bcnt);
    scan_kernel<<<1, 1024, 0, stream>>>(bcnt, boff, gcur);
    scatter_kernel<<<SCAT_BLOCKS, 256, 0, stream>>>(ei, gcur, pairs);
    dis_kernel<<<NB, 256, 0, stream>>>(pairs, boff, dis);
    counts_kernel<<<2, 256, 0, stream>>>(batch, counts);
    mm1_kernel<<<1024, 256, 0, stream>>>(x, W1, dis, p);
    gather1_kernel<<<NB, 256, 0, stream>>>(p, pairs, boff, dis, b1, h);
    mm2_kernel<<<1024, 256, 0, stream>>>(h, W2, dis, p);
    gather2_kernel<<<NB, 256, 0, stream>>>(p, pairs, boff, dis, b2, batch, sums);
    fc_kernel<<<N_GRAPHS, 64, 0, stream>>>(sums, counts, Wfc, bfc, out);
}

// Round 3
// 613.885 us; speedup vs baseline: 4.9217x; 4.9217x over previous
//
#include <hip/hip_runtime.h>

#define N_NODES   100000
#define N_EDGES   3200000
#define F_INP     128
#define HID       64
#define N_GRAPHS  512
#define N_CLASSES 2
#define NB        782                      // ceil(N/128) buckets of 128 target nodes
#define SCAT_BLOCKS 256
#define CHUNK     (N_EDGES / SCAT_BLOCKS)  // 12500, exact

// ---------- pass 1: global bucket histogram (LDS-aggregated) ----------
__global__ __launch_bounds__(256) void hist_kernel(const int* __restrict__ ei,
                                                   int* __restrict__ bcnt) {
    __shared__ int hist[NB];
    for (int i = threadIdx.x; i < NB; i += 256) hist[i] = 0;
    __syncthreads();
    const int e0 = blockIdx.x * CHUNK, e1 = e0 + CHUNK;
    for (int e = e0 + threadIdx.x; e < e1; e += 256)
        atomicAdd(&hist[ei[N_EDGES + e] >> 7], 1);
    __syncthreads();
    for (int i = threadIdx.x; i < NB; i += 256)
        if (hist[i]) atomicAdd(&bcnt[i], hist[i]);
}

// ---------- pass 2: exclusive scan over 782 buckets (one block) ----------
__global__ __launch_bounds__(1024) void scan_kernel(const int* __restrict__ bcnt,
                                                    int* __restrict__ boff,
                                                    int* __restrict__ gcur) {
    __shared__ int s[1024];
    const int tid = threadIdx.x;
    const int v = (tid < NB) ? bcnt[tid] : 0;
    s[tid] = v;
    __syncthreads();
    for (int d = 1; d < 1024; d <<= 1) {
        int t = (tid >= d) ? s[tid - d] : 0;
        __syncthreads();
        s[tid] += t;
        __syncthreads();
    }
    if (tid <= NB) {
        int ex = s[tid] - v;               // exclusive; tid==NB -> total == N_EDGES
        boff[tid] = ex;
        if (tid < NB) gcur[tid] = ex;
    }
}

// ---------- pass 3: localized scatter into bucket-sorted packed pairs ----------
// pairs[e] = r | ((c & 127) << 17);  r < 2^17
__global__ __launch_bounds__(256) void scatter_kernel(const int* __restrict__ ei,
                                                      int* __restrict__ gcur,
                                                      int* __restrict__ pairs) {
    __shared__ int hist[NB];
    __shared__ int lbase[NB];
    __shared__ int lcur[NB];
    for (int i = threadIdx.x; i < NB; i += 256) { hist[i] = 0; lcur[i] = 0; }
    __syncthreads();
    const int e0 = blockIdx.x * CHUNK, e1 = e0 + CHUNK;
    for (int e = e0 + threadIdx.x; e < e1; e += 256)
        atomicAdd(&hist[ei[N_EDGES + e] >> 7], 1);
    __syncthreads();
    for (int i = threadIdx.x; i < NB; i += 256)
        lbase[i] = hist[i] ? atomicAdd(&gcur[i], hist[i]) : 0;
    __syncthreads();
    for (int e = e0 + threadIdx.x; e < e1; e += 256) {
        int c = ei[N_EDGES + e];
        int r = ei[e];
        int b = c >> 7;
        int off = atomicAdd(&lcur[b], 1);
        pairs[lbase[b] + off] = r | ((c & 127) << 17);
    }
}

// ---------- pass 4: per-bucket CSR build (coalesced adj writes) + offs + dis ----------
__global__ __launch_bounds__(256) void csr_kernel(const int* __restrict__ pairs,
                                                  const int* __restrict__ boff,
                                                  int* __restrict__ adj,
                                                  int* __restrict__ offs,
                                                  float* __restrict__ dis) {
    __shared__ int cnt[128];
    __shared__ int sc[128];
    __shared__ int base[128];
    __shared__ int cur[128];
    const int tid = threadIdx.x;
    const int b = blockIdx.x;
    const int beg = boff[b], end = boff[b + 1];
    if (tid < 128) { cnt[tid] = 0; cur[tid] = 0; }
    __syncthreads();
    for (int e = beg + tid; e < end; e += 256)
        atomicAdd(&cnt[pairs[e] >> 17], 1);
    __syncthreads();
    if (tid < 128) sc[tid] = cnt[tid];
    __syncthreads();
    for (int d = 1; d < 128; d <<= 1) {
        int t = (tid >= d && tid < 128) ? sc[tid - d] : 0;
        __syncthreads();
        if (tid < 128) sc[tid] += t;
        __syncthreads();
    }
    if (tid < 128) base[tid] = beg + sc[tid] - cnt[tid];   // exclusive + bucket base
    __syncthreads();
    for (int e = beg + tid; e < end; e += 256) {
        int v = pairs[e];
        int lc = v >> 17;
        int o = atomicAdd(&cur[lc], 1);
        adj[base[lc] + o] = v & 131071;
    }
    const int n = (b << 7) + tid;
    if (tid < 128 && n < N_NODES) {
        offs[n] = base[tid];
        dis[n] = rsqrtf((float)cnt[tid] + 1.0f);           // +1 = self-loop
    }
    if (b == 0 && tid == 0) offs[N_NODES] = N_EDGES;
}

// ---------- per-graph node counts: batch is sorted -> binary search ----------
__global__ void counts_kernel(const int* __restrict__ batch, int* __restrict__ counts) {
    const int g = blockIdx.x * blockDim.x + threadIdx.x;
    if (g >= N_GRAPHS) return;
    int lo = 0, hi = N_NODES;
    while (lo < hi) { int m = (lo + hi) >> 1; if (batch[m] < g) lo = m + 1; else hi = m; }
    const int l0 = lo;
    lo = 0; hi = N_NODES;
    while (lo < hi) { int m = (lo + hi) >> 1; if (batch[m] < g + 1) lo = m + 1; else hi = m; }
    counts[g] = lo - l0;
}

// ---------- mm1: p = dis * (x @ W1)   [N,128]@[128,64] ----------
__global__ __launch_bounds__(256) void mm1_kernel(const float* __restrict__ x,
                                                  const float* __restrict__ W1,
                                                  const float* __restrict__ dis,
                                                  float* __restrict__ p) {
    const int lane = threadIdx.x & 63;
    const int wid  = threadIdx.x >> 6;
    float4 w[32];                      // column `lane` of W1 in regs
#pragma unroll
    for (int kk = 0; kk < 32; ++kk)
        w[kk] = make_float4(W1[(4 * kk + 0) * HID + lane], W1[(4 * kk + 1) * HID + lane],
                            W1[(4 * kk + 2) * HID + lane], W1[(4 * kk + 3) * HID + lane]);
    const int gw = blockIdx.x * 4 + wid;
    const int tw = gridDim.x * 4;
    for (int base = gw * 2; base < N_NODES; base += tw * 2) {
        const int r0 = base, r1 = base + 1;
        const float4* x0 = (const float4*)(x + (size_t)r0 * F_INP);
        const float4* x1 = (const float4*)(x + (size_t)r1 * F_INP);
        float a0 = 0.f, a1 = 0.f;
#pragma unroll
        for (int kk = 0; kk < 32; ++kk) {
            float4 v0 = x0[kk];
            float4 v1 = x1[kk];
            a0 += v0.x * w[kk].x + v0.y * w[kk].y + v0.z * w[kk].z + v0.w * w[kk].w;
            a1 += v1.x * w[kk].x + v1.y * w[kk].y + v1.z * w[kk].z + v1.w * w[kk].w;
        }
        p[(size_t)r0 * HID + lane] = dis[r0] * a0;
        p[(size_t)r1 * HID + lane] = dis[r1] * a1;
    }
}

// ---------- mm2: p = dis * (h @ W2)   [N,64]@[64,64] ----------
__global__ __launch_bounds__(256) void mm2_kernel(const float* __restrict__ h,
                                                  const float* __restrict__ W2,
                                                  const float* __restrict__ dis,
                                                  float* __restrict__ p) {
    const int lane = threadIdx.x & 63;
    const int wid  = threadIdx.x >> 6;
    float4 w[16];
#pragma unroll
    for (int kk = 0; kk < 16; ++kk)
        w[kk] = make_float4(W2[(4 * kk + 0) * HID + lane], W2[(4 * kk + 1) * HID + lane],
                            W2[(4 * kk + 2) * HID + lane], W2[(4 * kk + 3) * HID + lane]);
    const int gw = blockIdx.x * 4 + wid;
    const int tw = gridDim.x * 4;
    for (int base = gw * 2; base < N_NODES; base += tw * 2) {
        const int r0 = base, r1 = base + 1;
        const float4* h0 = (const float4*)(h + (size_t)r0 * HID);
        const float4* h1 = (const float4*)(h + (size_t)r1 * HID);
        float a0 = 0.f, a1 = 0.f;
#pragma unroll
        for (int kk = 0; kk < 16; ++kk) {
            float4 v0 = h0[kk];
            float4 v1 = h1[kk];
            a0 += v0.x * w[kk].x + v0.y * w[kk].y + v0.z * w[kk].z + v0.w * w[kk].w;
            a1 += v1.x * w[kk].x + v1.y * w[kk].y + v1.z * w[kk].z + v1.w * w[kk].w;
        }
        p[(size_t)r0 * HID + lane] = dis[r0] * a0;
        p[(size_t)r1 * HID + lane] = dis[r1] * a1;
    }
}

// ---------- gather1: h = relu(dis[c] * (p[c] + sum_{r->c} p[r]) + b1) ----------
__global__ __launch_bounds__(256) void gather1_kernel(const float* __restrict__ p,
                                                      const int* __restrict__ adj,
                                                      const int* __restrict__ offs,
                                                      const float* __restrict__ dis,
                                                      const float* __restrict__ b1,
                                                      float* __restrict__ h) {
    const int lane = threadIdx.x & 63;
    const int gwave = (blockIdx.x * blockDim.x + threadIdx.x) >> 6;
    const int nwaves = (gridDim.x * blockDim.x) >> 6;
    const float bj = b1[lane];
    for (int c = gwave; c < N_NODES; c += nwaves) {
        float acc = p[(size_t)c * HID + lane];          // self-loop
        int e = offs[c];
        const int end = offs[c + 1];
        for (; e + 3 < end; e += 4) {
            int r0 = adj[e], r1 = adj[e + 1], r2 = adj[e + 2], r3 = adj[e + 3];
            float m0 = p[(size_t)r0 * HID + lane];
            float m1 = p[(size_t)r1 * HID + lane];
            float m2 = p[(size_t)r2 * HID + lane];
            float m3 = p[(size_t)r3 * HID + lane];
            acc += (m0 + m1) + (m2 + m3);
        }
        for (; e < end; ++e)
            acc += p[(size_t)adj[e] * HID + lane];
        h[(size_t)c * HID + lane] = fmaxf(dis[c] * acc + bj, 0.f);
    }
}

// ---------- gather2 + fused mean-pool numerator ----------
__global__ __launch_bounds__(256) void gather2_kernel(const float* __restrict__ p,
                                                      const int* __restrict__ adj,
                                                      const int* __restrict__ offs,
                                                      const float* __restrict__ dis,
                                                      const float* __restrict__ b2,
                                                      const int* __restrict__ batch,
                                                      float* __restrict__ sums) {
    const int lane = threadIdx.x & 63;
    const int gwave = (blockIdx.x * blockDim.x + threadIdx.x) >> 6;
    const int nwaves = (gridDim.x * blockDim.x) >> 6;
    const float bj = b2[lane];
    for (int c = gwave; c < N_NODES; c += nwaves) {
        float acc = p[(size_t)c * HID + lane];
        int e = offs[c];
        const int end = offs[c + 1];
        for (; e + 3 < end; e += 4) {
            int r0 = adj[e], r1 = adj[e + 1], r2 = adj[e + 2], r3 = adj[e + 3];
            float m0 = p[(size_t)r0 * HID + lane];
            float m1 = p[(size_t)r1 * HID + lane];
            float m2 = p[(size_t)r2 * HID + lane];
            float m3 = p[(size_t)r3 * HID + lane];
            acc += (m0 + m1) + (m2 + m3);
        }
        for (; e < end; ++e)
            acc += p[(size_t)adj[e] * HID + lane];
        float v = fmaxf(dis[c] * acc + bj, 0.f);
        atomicAdd(&sums[(size_t)batch[c] * HID + lane], v);
    }
}

// ---------- final FC: out[g] = (sums[g]/max(count,1)) @ Wfc + bfc ----------
__global__ void fc_kernel(const float* __restrict__ sums, const int* __restrict__ counts,
                          const float* __restrict__ Wfc, const float* __restrict__ bfc,
                          float* __restrict__ out) {
    const int g = blockIdx.x;
    const int j = threadIdx.x;
    float cnt = fmaxf((float)counts[g], 1.0f);
    float pj = sums[(size_t)g * HID + j] / cnt;
    float a0 = pj * Wfc[j * N_CLASSES + 0];
    float a1 = pj * Wfc[j * N_CLASSES + 1];
    for (int off = 32; off > 0; off >>= 1) {
        a0 += __shfl_down(a0, off, 64);
        a1 += __shfl_down(a1, off, 64);
    }
    if (j == 0) {
        out[g * N_CLASSES + 0] = a0 + bfc[0];
        out[g * N_CLASSES + 1] = a1 + bfc[1];
    }
}

extern "C" void kernel_launch(void* const* d_in, const int* in_sizes, int n_in,
                              void* d_out, int out_size, void* d_ws, size_t ws_size,
                              hipStream_t stream) {
    const float* x     = (const float*)d_in[0];
    const int*   ei    = (const int*)d_in[1];   // [2,E]: row=ei[0:E], col=ei[E:2E]
    const int*   batch = (const int*)d_in[2];
    const float* W1    = (const float*)d_in[3];
    const float* b1    = (const float*)d_in[4];
    const float* W2    = (const float*)d_in[5];
    const float* b2    = (const float*)d_in[6];
    const float* Wfc   = (const float*)d_in[7];
    const float* bfc   = (const float*)d_in[8];
    float* out = (float*)d_out;

    char* ws = (char*)d_ws;
    size_t off = 0;
    auto alloc = [&](size_t bytes) -> void* {
        void* pp = ws + off;
        off += (bytes + 255) & ~(size_t)255;
        return pp;
    };
    int*   bcnt   = (int*)alloc((size_t)NB * 4);
    int*   boff   = (int*)alloc((size_t)(NB + 1) * 4);
    int*   gcur   = (int*)alloc((size_t)NB * 4);
    float* dis    = (float*)alloc((size_t)N_NODES * 4);
    int*   pairs  = (int*)alloc((size_t)N_EDGES * 4);
    int*   adj    = (int*)alloc((size_t)N_EDGES * 4);
    int*   offs   = (int*)alloc((size_t)(N_NODES + 1) * 4);
    float* p      = (float*)alloc((size_t)N_NODES * HID * 4);
    float* h      = (float*)alloc((size_t)N_NODES * HID * 4);
    float* sums   = (float*)alloc((size_t)N_GRAPHS * HID * 4);
    int*   counts = (int*)alloc((size_t)N_GRAPHS * 4);

    hipMemsetAsync(bcnt, 0, (size_t)NB * 4, stream);
    hipMemsetAsync(sums, 0, (size_t)N_GRAPHS * HID * 4, stream);

    hist_kernel<<<SCAT_BLOCKS, 256, 0, stream>>>(ei, bcnt);
    scan_kernel<<<1, 1024, 0, stream>>>(bcnt, boff, gcur);
    scatter_kernel<<<SCAT_BLOCKS, 256, 0, stream>>>(ei, gcur, pairs);
    csr_kernel<<<NB, 256, 0, stream>>>(pairs, boff, adj, offs, dis);
    counts_kernel<<<2, 256, 0, stream>>>(batch, counts);
    mm1_kernel<<<1024, 256, 0, stream>>>(x, W1, dis, p);
    gather1_kernel<<<2048, 256, 0, stream>>>(p, adj, offs, dis, b1, h);
    mm2_kernel<<<1024, 256, 0, stream>>>(h, W2, dis, p);
    gather2_kernel<<<2048, 256, 0, stream>>>(p, adj, offs, dis, b2, batch, sums);
    fc_kernel<<<N_GRAPHS, 64, 0, stream>>>(sums, counts, Wfc, bfc, out);
}

// Round 4
// 524.750 us; speedup vs baseline: 5.7577x; 1.1699x over previous
//
#include <hip/hip_runtime.h>

#define N_NODES   100000
#define N_EDGES   3200000
#define F_INP     128
#define HID       64
#define N_GRAPHS  512
#define N_CLASSES 2
#define NB        782                      // ceil(N/128) buckets of 128 target nodes
#define SCAT_BLOCKS 256
#define CHUNK     (N_EDGES / SCAT_BLOCKS)  // 12500, exact

// ---------- pass 1: global bucket histogram (LDS-aggregated) ----------
__global__ __launch_bounds__(256) void hist_kernel(const int* __restrict__ ei,
                                                   int* __restrict__ bcnt) {
    __shared__ int hist[NB];
    for (int i = threadIdx.x; i < NB; i += 256) hist[i] = 0;
    __syncthreads();
    const int e0 = blockIdx.x * CHUNK, e1 = e0 + CHUNK;
    for (int e = e0 + threadIdx.x; e < e1; e += 256)
        atomicAdd(&hist[ei[N_EDGES + e] >> 7], 1);
    __syncthreads();
    for (int i = threadIdx.x; i < NB; i += 256)
        if (hist[i]) atomicAdd(&bcnt[i], hist[i]);
}

// ---------- pass 2: exclusive scan over 782 buckets (one block) ----------
__global__ __launch_bounds__(1024) void scan_kernel(const int* __restrict__ bcnt,
                                                    int* __restrict__ boff,
                                                    int* __restrict__ gcur) {
    __shared__ int s[1024];
    const int tid = threadIdx.x;
    const int v = (tid < NB) ? bcnt[tid] : 0;
    s[tid] = v;
    __syncthreads();
    for (int d = 1; d < 1024; d <<= 1) {
        int t = (tid >= d) ? s[tid - d] : 0;
        __syncthreads();
        s[tid] += t;
        __syncthreads();
    }
    if (tid <= NB) {
        int ex = s[tid] - v;               // exclusive; tid==NB -> total == N_EDGES
        boff[tid] = ex;
        if (tid < NB) gcur[tid] = ex;
    }
}

// ---------- pass 3: localized scatter into bucket-sorted packed pairs ----------
// pairs[e] = r | ((c & 127) << 17);  r < 2^17
__global__ __launch_bounds__(256) void scatter_kernel(const int* __restrict__ ei,
                                                      int* __restrict__ gcur,
                                                      int* __restrict__ pairs) {
    __shared__ int hist[NB];
    __shared__ int lbase[NB];
    __shared__ int lcur[NB];
    for (int i = threadIdx.x; i < NB; i += 256) { hist[i] = 0; lcur[i] = 0; }
    __syncthreads();
    const int e0 = blockIdx.x * CHUNK, e1 = e0 + CHUNK;
    for (int e = e0 + threadIdx.x; e < e1; e += 256)
        atomicAdd(&hist[ei[N_EDGES + e] >> 7], 1);
    __syncthreads();
    for (int i = threadIdx.x; i < NB; i += 256)
        lbase[i] = hist[i] ? atomicAdd(&gcur[i], hist[i]) : 0;
    __syncthreads();
    for (int e = e0 + threadIdx.x; e < e1; e += 256) {
        int c = ei[N_EDGES + e];
        int r = ei[e];
        int b = c >> 7;
        int off = atomicAdd(&lcur[b], 1);
        pairs[lbase[b] + off] = r | ((c & 127) << 17);
    }
}

// ---------- pass 4: per-bucket CSR build (coalesced adj writes) + offs + dis ----------
__global__ __launch_bounds__(256) void csr_kernel(const int* __restrict__ pairs,
                                                  const int* __restrict__ boff,
                                                  int* __restrict__ adj,
                                                  int* __restrict__ offs,
                                                  float* __restrict__ dis) {
    __shared__ int cnt[128];
    __shared__ int sc[128];
    __shared__ int base[128];
    __shared__ int cur[128];
    const int tid = threadIdx.x;
    const int b = blockIdx.x;
    const int beg = boff[b], end = boff[b + 1];
    if (tid < 128) { cnt[tid] = 0; cur[tid] = 0; }
    __syncthreads();
    for (int e = beg + tid; e < end; e += 256)
        atomicAdd(&cnt[pairs[e] >> 17], 1);
    __syncthreads();
    if (tid < 128) sc[tid] = cnt[tid];
    __syncthreads();
    for (int d = 1; d < 128; d <<= 1) {
        int t = (tid >= d && tid < 128) ? sc[tid - d] : 0;
        __syncthreads();
        if (tid < 128) sc[tid] += t;
        __syncthreads();
    }
    if (tid < 128) base[tid] = beg + sc[tid] - cnt[tid];   // exclusive + bucket base
    __syncthreads();
    for (int e = beg + tid; e < end; e += 256) {
        int v = pairs[e];
        int lc = v >> 17;
        int o = atomicAdd(&cur[lc], 1);
        adj[base[lc] + o] = v & 131071;
    }
    const int n = (b << 7) + tid;
    if (tid < 128 && n < N_NODES) {
        offs[n] = base[tid];
        dis[n] = rsqrtf((float)cnt[tid] + 1.0f);           // +1 = self-loop
    }
    if (b == 0 && tid == 0) offs[N_NODES] = N_EDGES;
}

// ---------- per-graph node counts: batch is sorted -> binary search ----------
__global__ void counts_kernel(const int* __restrict__ batch, int* __restrict__ counts) {
    const int g = blockIdx.x * blockDim.x + threadIdx.x;
    if (g >= N_GRAPHS) return;
    int lo = 0, hi = N_NODES;
    while (lo < hi) { int m = (lo + hi) >> 1; if (batch[m] < g) lo = m + 1; else hi = m; }
    const int l0 = lo;
    lo = 0; hi = N_NODES;
    while (lo < hi) { int m = (lo + hi) >> 1; if (batch[m] < g + 1) lo = m + 1; else hi = m; }
    counts[g] = lo - l0;
}

// ---------- mm1: p = dis * (x @ W1)   [N,128]@[128,64], register-tiled ----------
// Block: 256 threads -> 64 rows x 64 cols. Thread (tx,ty): cols 4tx..4tx+3, rows 4ty..4ty+3.
// W staged in LDS [k][col] natural layout: ws[k*64+4tx] b128 reads are 2-way bank-aliased (free).
// x rows read directly from global (each row belongs to exactly one block -> read once).
__global__ __launch_bounds__(256) void mm1_kernel(const float* __restrict__ x,
                                                  const float* __restrict__ W1,
                                                  const float* __restrict__ dis,
                                                  float* __restrict__ p) {
    __shared__ float ws[F_INP * HID];
    for (int i = threadIdx.x; i < F_INP * HID / 4; i += 256)
        ((float4*)ws)[i] = ((const float4*)W1)[i];
    __syncthreads();
    const int tx = threadIdx.x & 15;
    const int ty = threadIdx.x >> 4;
    const int row0 = blockIdx.x * 64 + ty * 4;
    int r[4];
#pragma unroll
    for (int i = 0; i < 4; ++i) r[i] = min(row0 + i, N_NODES - 1);
    float acc[4][4] = {};
#pragma unroll 2
    for (int k = 0; k < F_INP; k += 4) {
        float4 a[4];
#pragma unroll
        for (int i = 0; i < 4; ++i)
            a[i] = *(const float4*)(x + (size_t)r[i] * F_INP + k);
        float4 w0 = *(const float4*)(ws + (k + 0) * HID + tx * 4);
        float4 w1 = *(const float4*)(ws + (k + 1) * HID + tx * 4);
        float4 w2 = *(const float4*)(ws + (k + 2) * HID + tx * 4);
        float4 w3 = *(const float4*)(ws + (k + 3) * HID + tx * 4);
#pragma unroll
        for (int i = 0; i < 4; ++i) {
            acc[i][0] += a[i].x * w0.x + a[i].y * w1.x + a[i].z * w2.x + a[i].w * w3.x;
            acc[i][1] += a[i].x * w0.y + a[i].y * w1.y + a[i].z * w2.y + a[i].w * w3.y;
            acc[i][2] += a[i].x * w0.z + a[i].y * w1.z + a[i].z * w2.z + a[i].w * w3.z;
            acc[i][3] += a[i].x * w0.w + a[i].y * w1.w + a[i].z * w2.w + a[i].w * w3.w;
        }
    }
#pragma unroll
    for (int i = 0; i < 4; ++i) {
        int rr = row0 + i;
        if (rr < N_NODES) {
            float d = dis[rr];
            float4 o = make_float4(d * acc[i][0], d * acc[i][1], d * acc[i][2], d * acc[i][3]);
            *(float4*)(p + (size_t)rr * HID + tx * 4) = o;
        }
    }
}

// ---------- mm2: p = dis * (h @ W2)   [N,64]@[64,64], same structure ----------
__global__ __launch_bounds__(256) void mm2_kernel(const float* __restrict__ h,
                                                  const float* __restrict__ W2,
                                                  const float* __restrict__ dis,
                                                  float* __restrict__ p) {
    __shared__ float ws[HID * HID];
    for (int i = threadIdx.x; i < HID * HID / 4; i += 256)
        ((float4*)ws)[i] = ((const float4*)W2)[i];
    __syncthreads();
    const int tx = threadIdx.x & 15;
    const int ty = threadIdx.x >> 4;
    const int row0 = blockIdx.x * 64 + ty * 4;
    int r[4];
#pragma unroll
    for (int i = 0; i < 4; ++i) r[i] = min(row0 + i, N_NODES - 1);
    float acc[4][4] = {};
#pragma unroll 2
    for (int k = 0; k < HID; k += 4) {
        float4 a[4];
#pragma unroll
        for (int i = 0; i < 4; ++i)
            a[i] = *(const float4*)(h + (size_t)r[i] * HID + k);
        float4 w0 = *(const float4*)(ws + (k + 0) * HID + tx * 4);
        float4 w1 = *(const float4*)(ws + (k + 1) * HID + tx * 4);
        float4 w2 = *(const float4*)(ws + (k + 2) * HID + tx * 4);
        float4 w3 = *(const float4*)(ws + (k + 3) * HID + tx * 4);
#pragma unroll
        for (int i = 0; i < 4; ++i) {
            acc[i][0] += a[i].x * w0.x + a[i].y * w1.x + a[i].z * w2.x + a[i].w * w3.x;
            acc[i][1] += a[i].x * w0.y + a[i].y * w1.y + a[i].z * w2.y + a[i].w * w3.y;
            acc[i][2] += a[i].x * w0.z + a[i].y * w1.z + a[i].z * w2.z + a[i].w * w3.z;
            acc[i][3] += a[i].x * w0.w + a[i].y * w1.w + a[i].z * w2.w + a[i].w * w3.w;
        }
    }
#pragma unroll
    for (int i = 0; i < 4; ++i) {
        int rr = row0 + i;
        if (rr < N_NODES) {
            float d = dis[rr];
            float4 o = make_float4(d * acc[i][0], d * acc[i][1], d * acc[i][2], d * acc[i][3]);
            *(float4*)(p + (size_t)rr * HID + tx * 4) = o;
        }
    }
}

// ---------- gather1: h = relu(dis[c] * (p[c] + sum_{r->c} p[r]) + b1) ----------
__global__ __launch_bounds__(256) void gather1_kernel(const float* __restrict__ p,
                                                      const int* __restrict__ adj,
                                                      const int* __restrict__ offs,
                                                      const float* __restrict__ dis,
                                                      const float* __restrict__ b1,
                                                      float* __restrict__ h) {
    const int lane = threadIdx.x & 63;
    const int gwave = (blockIdx.x * blockDim.x + threadIdx.x) >> 6;
    const int nwaves = (gridDim.x * blockDim.x) >> 6;
    const float bj = b1[lane];
    for (int c = gwave; c < N_NODES; c += nwaves) {
        float acc = p[(size_t)c * HID + lane];          // self-loop
        int e = offs[c];
        const int end = offs[c + 1];
        for (; e + 3 < end; e += 4) {
            int r0 = adj[e], r1 = adj[e + 1], r2 = adj[e + 2], r3 = adj[e + 3];
            float m0 = p[(size_t)r0 * HID + lane];
            float m1 = p[(size_t)r1 * HID + lane];
            float m2 = p[(size_t)r2 * HID + lane];
            float m3 = p[(size_t)r3 * HID + lane];
            acc += (m0 + m1) + (m2 + m3);
        }
        for (; e < end; ++e)
            acc += p[(size_t)adj[e] * HID + lane];
        h[(size_t)c * HID + lane] = fmaxf(dis[c] * acc + bj, 0.f);
    }
}

// ---------- gather2 + fused mean-pool numerator ----------
__global__ __launch_bounds__(256) void gather2_kernel(const float* __restrict__ p,
                                                      const int* __restrict__ adj,
                                                      const int* __restrict__ offs,
                                                      const float* __restrict__ dis,
                                                      const float* __restrict__ b2,
                                                      const int* __restrict__ batch,
                                                      float* __restrict__ sums) {
    const int lane = threadIdx.x & 63;
    const int gwave = (blockIdx.x * blockDim.x + threadIdx.x) >> 6;
    const int nwaves = (gridDim.x * blockDim.x) >> 6;
    const float bj = b2[lane];
    for (int c = gwave; c < N_NODES; c += nwaves) {
        float acc = p[(size_t)c * HID + lane];
        int e = offs[c];
        const int end = offs[c + 1];
        for (; e + 3 < end; e += 4) {
            int r0 = adj[e], r1 = adj[e + 1], r2 = adj[e + 2], r3 = adj[e + 3];
            float m0 = p[(size_t)r0 * HID + lane];
            float m1 = p[(size_t)r1 * HID + lane];
            float m2 = p[(size_t)r2 * HID + lane];
            float m3 = p[(size_t)r3 * HID + lane];
            acc += (m0 + m1) + (m2 + m3);
        }
        for (; e < end; ++e)
            acc += p[(size_t)adj[e] * HID + lane];
        float v = fmaxf(dis[c] * acc + bj, 0.f);
        atomicAdd(&sums[(size_t)batch[c] * HID + lane], v);
    }
}

// ---------- final FC: out[g] = (sums[g]/max(count,1)) @ Wfc + bfc ----------
__global__ void fc_kernel(const float* __restrict__ sums, const int* __restrict__ counts,
                          const float* __restrict__ Wfc, const float* __restrict__ bfc,
                          float* __restrict__ out) {
    const int g = blockIdx.x;
    const int j = threadIdx.x;
    float cnt = fmaxf((float)counts[g], 1.0f);
    float pj = sums[(size_t)g * HID + j] / cnt;
    float a0 = pj * Wfc[j * N_CLASSES + 0];
    float a1 = pj * Wfc[j * N_CLASSES + 1];
    for (int off = 32; off > 0; off >>= 1) {
        a0 += __shfl_down(a0, off, 64);
        a1 += __shfl_down(a1, off, 64);
    }
    if (j == 0) {
        out[g * N_CLASSES + 0] = a0 + bfc[0];
        out[g * N_CLASSES + 1] = a1 + bfc[1];
    }
}

extern "C" void kernel_launch(void* const* d_in, const int* in_sizes, int n_in,
                              void* d_out, int out_size, void* d_ws, size_t ws_size,
                              hipStream_t stream) {
    const float* x     = (const float*)d_in[0];
    const int*   ei    = (const int*)d_in[1];   // [2,E]: row=ei[0:E], col=ei[E:2E]
    const int*   batch = (const int*)d_in[2];
    const float* W1    = (const float*)d_in[3];
    const float* b1    = (const float*)d_in[4];
    const float* W2    = (const float*)d_in[5];
    const float* b2    = (const float*)d_in[6];
    const float* Wfc   = (const float*)d_in[7];
    const float* bfc   = (const float*)d_in[8];
    float* out = (float*)d_out;

    char* ws = (char*)d_ws;
    size_t off = 0;
    auto alloc = [&](size_t bytes) -> void* {
        void* pp = ws + off;
        off += (bytes + 255) & ~(size_t)255;
        return pp;
    };
    int*   bcnt   = (int*)alloc((size_t)NB * 4);
    int*   boff   = (int*)alloc((size_t)(NB + 1) * 4);
    int*   gcur   = (int*)alloc((size_t)NB * 4);
    float* dis    = (float*)alloc((size_t)N_NODES * 4);
    int*   pairs  = (int*)alloc((size_t)N_EDGES * 4);
    int*   adj    = (int*)alloc((size_t)N_EDGES * 4);
    int*   offs   = (int*)alloc((size_t)(N_NODES + 1) * 4);
    float* p      = (float*)alloc((size_t)N_NODES * HID * 4);
    float* h      = (float*)alloc((size_t)N_NODES * HID * 4);
    float* sums   = (float*)alloc((size_t)N_GRAPHS * HID * 4);
    int*   counts = (int*)alloc((size_t)N_GRAPHS * 4);

    hipMemsetAsync(bcnt, 0, (size_t)NB * 4, stream);
    hipMemsetAsync(sums, 0, (size_t)N_GRAPHS * HID * 4, stream);

    hist_kernel<<<SCAT_BLOCKS, 256, 0, stream>>>(ei, bcnt);
    scan_kernel<<<1, 1024, 0, stream>>>(bcnt, boff, gcur);
    scatter_kernel<<<SCAT_BLOCKS, 256, 0, stream>>>(ei, gcur, pairs);
    csr_kernel<<<NB, 256, 0, stream>>>(pairs, boff, adj, offs, dis);
    counts_kernel<<<2, 256, 0, stream>>>(batch, counts);
    mm1_kernel<<<(N_NODES + 63) / 64, 256, 0, stream>>>(x, W1, dis, p);
    gather1_kernel<<<2048, 256, 0, stream>>>(p, adj, offs, dis, b1, h);
    mm2_kernel<<<(N_NODES + 63) / 64, 256, 0, stream>>>(h, W2, dis, p);
    gather2_kernel<<<2048, 256, 0, stream>>>(p, adj, offs, dis, b2, batch, sums);
    fc_kernel<<<N_GRAPHS, 64, 0, stream>>>(sums, counts, Wfc, bfc, out);
}

// Round 5
// 464.401 us; speedup vs baseline: 6.5059x; 1.1299x over previous
//
#include <hip/hip_runtime.h>

#define N_NODES   100000
#define N_EDGES   3200000
#define F_INP     128
#define HID       64
#define N_GRAPHS  512
#define N_CLASSES 2
#define NB        782                      // ceil(N/128) buckets of 128 target nodes
#define SCAT_BLOCKS 256
#define CHUNK     (N_EDGES / SCAT_BLOCKS)  // 12500, exact

// bf16 helpers: RTN encode, exact decode (bits<<16)
__device__ __forceinline__ unsigned short f2bf(float f) {
    unsigned int u = __float_as_uint(f);
    return (unsigned short)((u + 0x7FFFu + ((u >> 16) & 1u)) >> 16);
}
__device__ __forceinline__ float bf2f(unsigned short b) {
    return __uint_as_float(((unsigned int)b) << 16);
}

// ---------- pass 1: global bucket histogram (LDS-aggregated) ----------
__global__ __launch_bounds__(256) void hist_kernel(const int* __restrict__ ei,
                                                   int* __restrict__ bcnt) {
    __shared__ int hist[NB];
    for (int i = threadIdx.x; i < NB; i += 256) hist[i] = 0;
    __syncthreads();
    const int e0 = blockIdx.x * CHUNK, e1 = e0 + CHUNK;
    for (int e = e0 + threadIdx.x; e < e1; e += 256)
        atomicAdd(&hist[ei[N_EDGES + e] >> 7], 1);
    __syncthreads();
    for (int i = threadIdx.x; i < NB; i += 256)
        if (hist[i]) atomicAdd(&bcnt[i], hist[i]);
}

// ---------- pass 2: exclusive scan over 782 buckets (one block) ----------
__global__ __launch_bounds__(1024) void scan_kernel(const int* __restrict__ bcnt,
                                                    int* __restrict__ boff,
                                                    int* __restrict__ gcur) {
    __shared__ int s[1024];
    const int tid = threadIdx.x;
    const int v = (tid < NB) ? bcnt[tid] : 0;
    s[tid] = v;
    __syncthreads();
    for (int d = 1; d < 1024; d <<= 1) {
        int t = (tid >= d) ? s[tid - d] : 0;
        __syncthreads();
        s[tid] += t;
        __syncthreads();
    }
    if (tid <= NB) {
        int ex = s[tid] - v;               // exclusive; tid==NB -> total == N_EDGES
        boff[tid] = ex;
        if (tid < NB) gcur[tid] = ex;
    }
}

// ---------- pass 3: localized scatter into bucket-sorted packed pairs ----------
// pairs[e] = r | ((c & 127) << 17);  r < 2^17
__global__ __launch_bounds__(256) void scatter_kernel(const int* __restrict__ ei,
                                                      int* __restrict__ gcur,
                                                      int* __restrict__ pairs) {
    __shared__ int hist[NB];
    __shared__ int lbase[NB];
    __shared__ int lcur[NB];
    for (int i = threadIdx.x; i < NB; i += 256) { hist[i] = 0; lcur[i] = 0; }
    __syncthreads();
    const int e0 = blockIdx.x * CHUNK, e1 = e0 + CHUNK;
    for (int e = e0 + threadIdx.x; e < e1; e += 256)
        atomicAdd(&hist[ei[N_EDGES + e] >> 7], 1);
    __syncthreads();
    for (int i = threadIdx.x; i < NB; i += 256)
        lbase[i] = hist[i] ? atomicAdd(&gcur[i], hist[i]) : 0;
    __syncthreads();
    for (int e = e0 + threadIdx.x; e < e1; e += 256) {
        int c = ei[N_EDGES + e];
        int r = ei[e];
        int b = c >> 7;
        int off = atomicAdd(&lcur[b], 1);
        pairs[lbase[b] + off] = r | ((c & 127) << 17);
    }
}

// ---------- pass 4: per-bucket CSR build (coalesced adj writes) + offs + dis ----------
__global__ __launch_bounds__(256) void csr_kernel(const int* __restrict__ pairs,
                                                  const int* __restrict__ boff,
                                                  int* __restrict__ adj,
                                                  int* __restrict__ offs,
                                                  float* __restrict__ dis) {
    __shared__ int cnt[128];
    __shared__ int sc[128];
    __shared__ int base[128];
    __shared__ int cur[128];
    const int tid = threadIdx.x;
    const int b = blockIdx.x;
    const int beg = boff[b], end = boff[b + 1];
    if (tid < 128) { cnt[tid] = 0; cur[tid] = 0; }
    __syncthreads();
    for (int e = beg + tid; e < end; e += 256)
        atomicAdd(&cnt[pairs[e] >> 17], 1);
    __syncthreads();
    if (tid < 128) sc[tid] = cnt[tid];
    __syncthreads();
    for (int d = 1; d < 128; d <<= 1) {
        int t = (tid >= d && tid < 128) ? sc[tid - d] : 0;
        __syncthreads();
        if (tid < 128) sc[tid] += t;
        __syncthreads();
    }
    if (tid < 128) base[tid] = beg + sc[tid] - cnt[tid];   // exclusive + bucket base
    __syncthreads();
    for (int e = beg + tid; e < end; e += 256) {
        int v = pairs[e];
        int lc = v >> 17;
        int o = atomicAdd(&cur[lc], 1);
        adj[base[lc] + o] = v & 131071;
    }
    const int n = (b << 7) + tid;
    if (tid < 128 && n < N_NODES) {
        offs[n] = base[tid];
        dis[n] = rsqrtf((float)cnt[tid] + 1.0f);           // +1 = self-loop
    }
    if (b == 0 && tid == 0) offs[N_NODES] = N_EDGES;
}

// ---------- per-graph node counts: batch is sorted -> binary search ----------
__global__ void counts_kernel(const int* __restrict__ batch, int* __restrict__ counts) {
    const int g = blockIdx.x * blockDim.x + threadIdx.x;
    if (g >= N_GRAPHS) return;
    int lo = 0, hi = N_NODES;
    while (lo < hi) { int m = (lo + hi) >> 1; if (batch[m] < g) lo = m + 1; else hi = m; }
    const int l0 = lo;
    lo = 0; hi = N_NODES;
    while (lo < hi) { int m = (lo + hi) >> 1; if (batch[m] < g + 1) lo = m + 1; else hi = m; }
    counts[g] = lo - l0;
}

// ---------- mm1: p = bf16(dis * (x @ W1))   [N,128]@[128,64], register-tiled ----------
__global__ __launch_bounds__(256) void mm1_kernel(const float* __restrict__ x,
                                                  const float* __restrict__ W1,
                                                  const float* __restrict__ dis,
                                                  unsigned short* __restrict__ p) {
    __shared__ float ws[F_INP * HID];
    for (int i = threadIdx.x; i < F_INP * HID / 4; i += 256)
        ((float4*)ws)[i] = ((const float4*)W1)[i];
    __syncthreads();
    const int tx = threadIdx.x & 15;
    const int ty = threadIdx.x >> 4;
    const int row0 = blockIdx.x * 64 + ty * 4;
    int r[4];
#pragma unroll
    for (int i = 0; i < 4; ++i) r[i] = min(row0 + i, N_NODES - 1);
    float acc[4][4] = {};
#pragma unroll 2
    for (int k = 0; k < F_INP; k += 4) {
        float4 a[4];
#pragma unroll
        for (int i = 0; i < 4; ++i)
            a[i] = *(const float4*)(x + (size_t)r[i] * F_INP + k);
        float4 w0 = *(const float4*)(ws + (k + 0) * HID + tx * 4);
        float4 w1 = *(const float4*)(ws + (k + 1) * HID + tx * 4);
        float4 w2 = *(const float4*)(ws + (k + 2) * HID + tx * 4);
        float4 w3 = *(const float4*)(ws + (k + 3) * HID + tx * 4);
#pragma unroll
        for (int i = 0; i < 4; ++i) {
            acc[i][0] += a[i].x * w0.x + a[i].y * w1.x + a[i].z * w2.x + a[i].w * w3.x;
            acc[i][1] += a[i].x * w0.y + a[i].y * w1.y + a[i].z * w2.y + a[i].w * w3.y;
            acc[i][2] += a[i].x * w0.z + a[i].y * w1.z + a[i].z * w2.z + a[i].w * w3.z;
            acc[i][3] += a[i].x * w0.w + a[i].y * w1.w + a[i].z * w2.w + a[i].w * w3.w;
        }
    }
#pragma unroll
    for (int i = 0; i < 4; ++i) {
        int rr = row0 + i;
        if (rr < N_NODES) {
            float d = dis[rr];
            ushort4 o;
            o.x = f2bf(d * acc[i][0]);
            o.y = f2bf(d * acc[i][1]);
            o.z = f2bf(d * acc[i][2]);
            o.w = f2bf(d * acc[i][3]);
            *(ushort4*)(p + (size_t)rr * HID + tx * 4) = o;
        }
    }
}

// ---------- mm2: p = bf16(dis * (h @ W2))   [N,64]@[64,64] ----------
__global__ __launch_bounds__(256) void mm2_kernel(const float* __restrict__ h,
                                                  const float* __restrict__ W2,
                                                  const float* __restrict__ dis,
                                                  unsigned short* __restrict__ p) {
    __shared__ float ws[HID * HID];
    for (int i = threadIdx.x; i < HID * HID / 4; i += 256)
        ((float4*)ws)[i] = ((const float4*)W2)[i];
    __syncthreads();
    const int tx = threadIdx.x & 15;
    const int ty = threadIdx.x >> 4;
    const int row0 = blockIdx.x * 64 + ty * 4;
    int r[4];
#pragma unroll
    for (int i = 0; i < 4; ++i) r[i] = min(row0 + i, N_NODES - 1);
    float acc[4][4] = {};
#pragma unroll 2
    for (int k = 0; k < HID; k += 4) {
        float4 a[4];
#pragma unroll
        for (int i = 0; i < 4; ++i)
            a[i] = *(const float4*)(h + (size_t)r[i] * HID + k);
        float4 w0 = *(const float4*)(ws + (k + 0) * HID + tx * 4);
        float4 w1 = *(const float4*)(ws + (k + 1) * HID + tx * 4);
        float4 w2 = *(const float4*)(ws + (k + 2) * HID + tx * 4);
        float4 w3 = *(const float4*)(ws + (k + 3) * HID + tx * 4);
#pragma unroll
        for (int i = 0; i < 4; ++i) {
            acc[i][0] += a[i].x * w0.x + a[i].y * w1.x + a[i].z * w2.x + a[i].w * w3.x;
            acc[i][1] += a[i].x * w0.y + a[i].y * w1.y + a[i].z * w2.y + a[i].w * w3.y;
            acc[i][2] += a[i].x * w0.z + a[i].y * w1.z + a[i].z * w2.z + a[i].w * w3.z;
            acc[i][3] += a[i].x * w0.w + a[i].y * w1.w + a[i].z * w2.w + a[i].w * w3.w;
        }
    }
#pragma unroll
    for (int i = 0; i < 4; ++i) {
        int rr = row0 + i;
        if (rr < N_NODES) {
            float d = dis[rr];
            ushort4 o;
            o.x = f2bf(d * acc[i][0]);
            o.y = f2bf(d * acc[i][1]);
            o.z = f2bf(d * acc[i][2]);
            o.w = f2bf(d * acc[i][3]);
            *(ushort4*)(p + (size_t)rr * HID + tx * 4) = o;
        }
    }
}

// ---------- gather1: h = relu(dis[c] * (p[c] + sum_{r->c} p[r]) + b1), p in bf16 ----------
__global__ __launch_bounds__(256) void gather1_kernel(const unsigned short* __restrict__ p,
                                                      const int* __restrict__ adj,
                                                      const int* __restrict__ offs,
                                                      const float* __restrict__ dis,
                                                      const float* __restrict__ b1,
                                                      float* __restrict__ h) {
    const int lane = threadIdx.x & 63;
    const int gwave = (blockIdx.x * blockDim.x + threadIdx.x) >> 6;
    const int nwaves = (gridDim.x * blockDim.x) >> 6;
    const float bj = b1[lane];
    for (int c = gwave; c < N_NODES; c += nwaves) {
        float acc = bf2f(p[(size_t)c * HID + lane]);    // self-loop
        int e = offs[c];
        const int end = offs[c + 1];
        for (; e + 3 < end; e += 4) {
            int r0 = adj[e], r1 = adj[e + 1], r2 = adj[e + 2], r3 = adj[e + 3];
            float m0 = bf2f(p[(size_t)r0 * HID + lane]);
            float m1 = bf2f(p[(size_t)r1 * HID + lane]);
            float m2 = bf2f(p[(size_t)r2 * HID + lane]);
            float m3 = bf2f(p[(size_t)r3 * HID + lane]);
            acc += (m0 + m1) + (m2 + m3);
        }
        for (; e < end; ++e)
            acc += bf2f(p[(size_t)adj[e] * HID + lane]);
        h[(size_t)c * HID + lane] = fmaxf(dis[c] * acc + bj, 0.f);
    }
}

// ---------- gather2 + fused mean-pool numerator, p in bf16 ----------
__global__ __launch_bounds__(256) void gather2_kernel(const unsigned short* __restrict__ p,
                                                      const int* __restrict__ adj,
                                                      const int* __restrict__ offs,
                                                      const float* __restrict__ dis,
                                                      const float* __restrict__ b2,
                                                      const int* __restrict__ batch,
                                                      float* __restrict__ sums) {
    const int lane = threadIdx.x & 63;
    const int gwave = (blockIdx.x * blockDim.x + threadIdx.x) >> 6;
    const int nwaves = (gridDim.x * blockDim.x) >> 6;
    const float bj = b2[lane];
    for (int c = gwave; c < N_NODES; c += nwaves) {
        float acc = bf2f(p[(size_t)c * HID + lane]);
        int e = offs[c];
        const int end = offs[c + 1];
        for (; e + 3 < end; e += 4) {
            int r0 = adj[e], r1 = adj[e + 1], r2 = adj[e + 2], r3 = adj[e + 3];
            float m0 = bf2f(p[(size_t)r0 * HID + lane]);
            float m1 = bf2f(p[(size_t)r1 * HID + lane]);
            float m2 = bf2f(p[(size_t)r2 * HID + lane]);
            float m3 = bf2f(p[(size_t)r3 * HID + lane]);
            acc += (m0 + m1) + (m2 + m3);
        }
        for (; e < end; ++e)
            acc += bf2f(p[(size_t)adj[e] * HID + lane]);
        float v = fmaxf(dis[c] * acc + bj, 0.f);
        atomicAdd(&sums[(size_t)batch[c] * HID + lane], v);
    }
}

// ---------- final FC: out[g] = (sums[g]/max(count,1)) @ Wfc + bfc ----------
__global__ void fc_kernel(const float* __restrict__ sums, const int* __restrict__ counts,
                          const float* __restrict__ Wfc, const float* __restrict__ bfc,
                          float* __restrict__ out) {
    const int g = blockIdx.x;
    const int j = threadIdx.x;
    float cnt = fmaxf((float)counts[g], 1.0f);
    float pj = sums[(size_t)g * HID + j] / cnt;
    float a0 = pj * Wfc[j * N_CLASSES + 0];
    float a1 = pj * Wfc[j * N_CLASSES + 1];
    for (int off = 32; off > 0; off >>= 1) {
        a0 += __shfl_down(a0, off, 64);
        a1 += __shfl_down(a1, off, 64);
    }
    if (j == 0) {
        out[g * N_CLASSES + 0] = a0 + bfc[0];
        out[g * N_CLASSES + 1] = a1 + bfc[1];
    }
}

extern "C" void kernel_launch(void* const* d_in, const int* in_sizes, int n_in,
                              void* d_out, int out_size, void* d_ws, size_t ws_size,
                              hipStream_t stream) {
    const float* x     = (const float*)d_in[0];
    const int*   ei    = (const int*)d_in[1];   // [2,E]: row=ei[0:E], col=ei[E:2E]
    const int*   batch = (const int*)d_in[2];
    const float* W1    = (const float*)d_in[3];
    const float* b1    = (const float*)d_in[4];
    const float* W2    = (const float*)d_in[5];
    const float* b2    = (const float*)d_in[6];
    const float* Wfc   = (const float*)d_in[7];
    const float* bfc   = (const float*)d_in[8];
    float* out = (float*)d_out;

    char* ws = (char*)d_ws;
    size_t off = 0;
    auto alloc = [&](size_t bytes) -> void* {
        void* pp = ws + off;
        off += (bytes + 255) & ~(size_t)255;
        return pp;
    };
    int*   bcnt   = (int*)alloc((size_t)NB * 4);
    int*   boff   = (int*)alloc((size_t)(NB + 1) * 4);
    int*   gcur   = (int*)alloc((size_t)NB * 4);
    float* dis    = (float*)alloc((size_t)N_NODES * 4);
    int*   pairs  = (int*)alloc((size_t)N_EDGES * 4);
    int*   adj    = (int*)alloc((size_t)N_EDGES * 4);
    int*   offs   = (int*)alloc((size_t)(N_NODES + 1) * 4);
    unsigned short* p = (unsigned short*)alloc((size_t)N_NODES * HID * 2);
    float* h      = (float*)alloc((size_t)N_NODES * HID * 4);
    float* sums   = (float*)alloc((size_t)N_GRAPHS * HID * 4);
    int*   counts = (int*)alloc((size_t)N_GRAPHS * 4);

    hipMemsetAsync(bcnt, 0, (size_t)NB * 4, stream);
    hipMemsetAsync(sums, 0, (size_t)N_GRAPHS * HID * 4, stream);

    hist_kernel<<<SCAT_BLOCKS, 256, 0, stream>>>(ei, bcnt);
    scan_kernel<<<1, 1024, 0, stream>>>(bcnt, boff, gcur);
    scatter_kernel<<<SCAT_BLOCKS, 256, 0, stream>>>(ei, gcur, pairs);
    csr_kernel<<<NB, 256, 0, stream>>>(pairs, boff, adj, offs, dis);
    counts_kernel<<<2, 256, 0, stream>>>(batch, counts);
    mm1_kernel<<<(N_NODES + 63) / 64, 256, 0, stream>>>(x, W1, dis, p);
    gather1_kernel<<<2048, 256, 0, stream>>>(p, adj, offs, dis, b1, h);
    mm2_kernel<<<(N_NODES + 63) / 64, 256, 0, stream>>>(h, W2, dis, p);
    gather2_kernel<<<2048, 256, 0, stream>>>(p, adj, offs, dis, b2, batch, sums);
    fc_kernel<<<N_GRAPHS, 64, 0, stream>>>(sums, counts, Wfc, bfc, out);
}

// Round 6
// 386.665 us; speedup vs baseline: 7.8139x; 1.2010x over previous
//
#include <hip/hip_runtime.h>

#define N_NODES   100000
#define N_EDGES   3200000
#define F_INP     128
#define HID       64
#define N_GRAPHS  512
#define N_CLASSES 2
#define NB        782                      // ceil(N/128) buckets of 128 target nodes
#define SCAT_BLOCKS 256
#define CHUNK     (N_EDGES / SCAT_BLOCKS)  // 12500, exact

// bf16 helpers: RTN encode; decode low/high halves of a packed u32
__device__ __forceinline__ unsigned short f2bf(float f) {
    unsigned int u = __float_as_uint(f);
    return (unsigned short)((u + 0x7FFFu + ((u >> 16) & 1u)) >> 16);
}
__device__ __forceinline__ float bf_lo(unsigned int u) { return __uint_as_float(u << 16); }
__device__ __forceinline__ float bf_hi(unsigned int u) { return __uint_as_float(u & 0xFFFF0000u); }

// ---------- pass 1: global bucket histogram (LDS-aggregated) ----------
__global__ __launch_bounds__(256) void hist_kernel(const int* __restrict__ ei,
                                                   int* __restrict__ bcnt) {
    __shared__ int hist[NB];
    for (int i = threadIdx.x; i < NB; i += 256) hist[i] = 0;
    __syncthreads();
    const int e0 = blockIdx.x * CHUNK, e1 = e0 + CHUNK;
    for (int e = e0 + threadIdx.x; e < e1; e += 256)
        atomicAdd(&hist[ei[N_EDGES + e] >> 7], 1);
    __syncthreads();
    for (int i = threadIdx.x; i < NB; i += 256)
        if (hist[i]) atomicAdd(&bcnt[i], hist[i]);
}

// ---------- pass 2: exclusive scan over 782 buckets (one block) ----------
__global__ __launch_bounds__(1024) void scan_kernel(const int* __restrict__ bcnt,
                                                    int* __restrict__ boff,
                                                    int* __restrict__ gcur) {
    __shared__ int s[1024];
    const int tid = threadIdx.x;
    const int v = (tid < NB) ? bcnt[tid] : 0;
    s[tid] = v;
    __syncthreads();
    for (int d = 1; d < 1024; d <<= 1) {
        int t = (tid >= d) ? s[tid - d] : 0;
        __syncthreads();
        s[tid] += t;
        __syncthreads();
    }
    if (tid <= NB) {
        int ex = s[tid] - v;               // exclusive; tid==NB -> total == N_EDGES
        boff[tid] = ex;
        if (tid < NB) gcur[tid] = ex;
    }
}

// ---------- pass 3: localized scatter into bucket-sorted packed pairs ----------
// pairs[e] = r | ((c & 127) << 17);  r < 2^17
__global__ __launch_bounds__(256) void scatter_kernel(const int* __restrict__ ei,
                                                      int* __restrict__ gcur,
                                                      int* __restrict__ pairs) {
    __shared__ int hist[NB];
    __shared__ int lbase[NB];
    __shared__ int lcur[NB];
    for (int i = threadIdx.x; i < NB; i += 256) { hist[i] = 0; lcur[i] = 0; }
    __syncthreads();
    const int e0 = blockIdx.x * CHUNK, e1 = e0 + CHUNK;
    for (int e = e0 + threadIdx.x; e < e1; e += 256)
        atomicAdd(&hist[ei[N_EDGES + e] >> 7], 1);
    __syncthreads();
    for (int i = threadIdx.x; i < NB; i += 256)
        lbase[i] = hist[i] ? atomicAdd(&gcur[i], hist[i]) : 0;
    __syncthreads();
    for (int e = e0 + threadIdx.x; e < e1; e += 256) {
        int c = ei[N_EDGES + e];
        int r = ei[e];
        int b = c >> 7;
        int off = atomicAdd(&lcur[b], 1);
        pairs[lbase[b] + off] = r | ((c & 127) << 17);
    }
}

// ---------- pass 4: per-bucket CSR build (coalesced adj writes) + offs + dis ----------
__global__ __launch_bounds__(256) void csr_kernel(const int* __restrict__ pairs,
                                                  const int* __restrict__ boff,
                                                  int* __restrict__ adj,
                                                  int* __restrict__ offs,
                                                  float* __restrict__ dis) {
    __shared__ int cnt[128];
    __shared__ int sc[128];
    __shared__ int base[128];
    __shared__ int cur[128];
    const int tid = threadIdx.x;
    const int b = blockIdx.x;
    const int beg = boff[b], end = boff[b + 1];
    if (tid < 128) { cnt[tid] = 0; cur[tid] = 0; }
    __syncthreads();
    for (int e = beg + tid; e < end; e += 256)
        atomicAdd(&cnt[pairs[e] >> 17], 1);
    __syncthreads();
    if (tid < 128) sc[tid] = cnt[tid];
    __syncthreads();
    for (int d = 1; d < 128; d <<= 1) {
        int t = (tid >= d && tid < 128) ? sc[tid - d] : 0;
        __syncthreads();
        if (tid < 128) sc[tid] += t;
        __syncthreads();
    }
    if (tid < 128) base[tid] = beg + sc[tid] - cnt[tid];   // exclusive + bucket base
    __syncthreads();
    for (int e = beg + tid; e < end; e += 256) {
        int v = pairs[e];
        int lc = v >> 17;
        int o = atomicAdd(&cur[lc], 1);
        adj[base[lc] + o] = v & 131071;
    }
    const int n = (b << 7) + tid;
    if (tid < 128 && n < N_NODES) {
        offs[n] = base[tid];
        dis[n] = rsqrtf((float)cnt[tid] + 1.0f);           // +1 = self-loop
    }
    if (b == 0 && tid == 0) offs[N_NODES] = N_EDGES;
}

// ---------- per-graph node counts: batch is sorted -> binary search ----------
__global__ void counts_kernel(const int* __restrict__ batch, int* __restrict__ counts) {
    const int g = blockIdx.x * blockDim.x + threadIdx.x;
    if (g >= N_GRAPHS) return;
    int lo = 0, hi = N_NODES;
    while (lo < hi) { int m = (lo + hi) >> 1; if (batch[m] < g) lo = m + 1; else hi = m; }
    const int l0 = lo;
    lo = 0; hi = N_NODES;
    while (lo < hi) { int m = (lo + hi) >> 1; if (batch[m] < g + 1) lo = m + 1; else hi = m; }
    counts[g] = lo - l0;
}

// ---------- mm1: p = bf16(dis * (x @ W1))   [N,128]@[128,64], register-tiled ----------
__global__ __launch_bounds__(256) void mm1_kernel(const float* __restrict__ x,
                                                  const float* __restrict__ W1,
                                                  const float* __restrict__ dis,
                                                  unsigned short* __restrict__ p) {
    __shared__ float ws[F_INP * HID];
    for (int i = threadIdx.x; i < F_INP * HID / 4; i += 256)
        ((float4*)ws)[i] = ((const float4*)W1)[i];
    __syncthreads();
    const int tx = threadIdx.x & 15;
    const int ty = threadIdx.x >> 4;
    const int row0 = blockIdx.x * 64 + ty * 4;
    int r[4];
#pragma unroll
    for (int i = 0; i < 4; ++i) r[i] = min(row0 + i, N_NODES - 1);
    float acc[4][4] = {};
#pragma unroll 2
    for (int k = 0; k < F_INP; k += 4) {
        float4 a[4];
#pragma unroll
        for (int i = 0; i < 4; ++i)
            a[i] = *(const float4*)(x + (size_t)r[i] * F_INP + k);
        float4 w0 = *(const float4*)(ws + (k + 0) * HID + tx * 4);
        float4 w1 = *(const float4*)(ws + (k + 1) * HID + tx * 4);
        float4 w2 = *(const float4*)(ws + (k + 2) * HID + tx * 4);
        float4 w3 = *(const float4*)(ws + (k + 3) * HID + tx * 4);
#pragma unroll
        for (int i = 0; i < 4; ++i) {
            acc[i][0] += a[i].x * w0.x + a[i].y * w1.x + a[i].z * w2.x + a[i].w * w3.x;
            acc[i][1] += a[i].x * w0.y + a[i].y * w1.y + a[i].z * w2.y + a[i].w * w3.y;
            acc[i][2] += a[i].x * w0.z + a[i].y * w1.z + a[i].z * w2.z + a[i].w * w3.z;
            acc[i][3] += a[i].x * w0.w + a[i].y * w1.w + a[i].z * w2.w + a[i].w * w3.w;
        }
    }
#pragma unroll
    for (int i = 0; i < 4; ++i) {
        int rr = row0 + i;
        if (rr < N_NODES) {
            float d = dis[rr];
            ushort4 o;
            o.x = f2bf(d * acc[i][0]);
            o.y = f2bf(d * acc[i][1]);
            o.z = f2bf(d * acc[i][2]);
            o.w = f2bf(d * acc[i][3]);
            *(ushort4*)(p + (size_t)rr * HID + tx * 4) = o;
        }
    }
}

// ---------- mm2: p = bf16(dis * (h @ W2))   [N,64]@[64,64] ----------
__global__ __launch_bounds__(256) void mm2_kernel(const float* __restrict__ h,
                                                  const float* __restrict__ W2,
                                                  const float* __restrict__ dis,
                                                  unsigned short* __restrict__ p) {
    __shared__ float ws[HID * HID];
    for (int i = threadIdx.x; i < HID * HID / 4; i += 256)
        ((float4*)ws)[i] = ((const float4*)W2)[i];
    __syncthreads();
    const int tx = threadIdx.x & 15;
    const int ty = threadIdx.x >> 4;
    const int row0 = blockIdx.x * 64 + ty * 4;
    int r[4];
#pragma unroll
    for (int i = 0; i < 4; ++i) r[i] = min(row0 + i, N_NODES - 1);
    float acc[4][4] = {};
#pragma unroll 2
    for (int k = 0; k < HID; k += 4) {
        float4 a[4];
#pragma unroll
        for (int i = 0; i < 4; ++i)
            a[i] = *(const float4*)(h + (size_t)r[i] * HID + k);
        float4 w0 = *(const float4*)(ws + (k + 0) * HID + tx * 4);
        float4 w1 = *(const float4*)(ws + (k + 1) * HID + tx * 4);
        float4 w2 = *(const float4*)(ws + (k + 2) * HID + tx * 4);
        float4 w3 = *(const float4*)(ws + (k + 3) * HID + tx * 4);
#pragma unroll
        for (int i = 0; i < 4; ++i) {
            acc[i][0] += a[i].x * w0.x + a[i].y * w1.x + a[i].z * w2.x + a[i].w * w3.x;
            acc[i][1] += a[i].x * w0.y + a[i].y * w1.y + a[i].z * w2.y + a[i].w * w3.y;
            acc[i][2] += a[i].x * w0.z + a[i].y * w1.z + a[i].z * w2.z + a[i].w * w3.z;
            acc[i][3] += a[i].x * w0.w + a[i].y * w1.w + a[i].z * w2.w + a[i].w * w3.w;
        }
    }
#pragma unroll
    for (int i = 0; i < 4; ++i) {
        int rr = row0 + i;
        if (rr < N_NODES) {
            float d = dis[rr];
            ushort4 o;
            o.x = f2bf(d * acc[i][0]);
            o.y = f2bf(d * acc[i][1]);
            o.z = f2bf(d * acc[i][2]);
            o.w = f2bf(d * acc[i][3]);
            *(ushort4*)(p + (size_t)rr * HID + tx * 4) = o;
        }
    }
}

// ---------- high-MLP gather core: 8 rows per dwordx4, 16 edges/iter ----------
// lane L: q = L>>3 (row slot), g = L&7 (feature octet, feats 8g..8g+7)
// acc[j] = feature 8g+j partial sum over this lane's row slots.
// After butterfly over q (xor 8,16,32), every lane has the full row sum;
// lane L extracts feature 8g+q.
__device__ __forceinline__ float gather_node(const unsigned short* __restrict__ p,
                                             const int* __restrict__ adj,
                                             int c, int beg, int end, int q, int g) {
    float acc[8];
    {   // self-loop row, counted once via q==0 lanes
        uint4 s = *(const uint4*)(p + (size_t)c * HID + g * 8);
        float sm = (q == 0) ? 1.f : 0.f;
        acc[0] = sm * bf_lo(s.x); acc[1] = sm * bf_hi(s.x);
        acc[2] = sm * bf_lo(s.y); acc[3] = sm * bf_hi(s.y);
        acc[4] = sm * bf_lo(s.z); acc[5] = sm * bf_hi(s.z);
        acc[6] = sm * bf_lo(s.w); acc[7] = sm * bf_hi(s.w);
    }
    int e = beg;
    for (; e + 16 <= end; e += 16) {            // full double iteration, no masks
        int r0 = adj[e + q];
        int r1 = adj[e + 8 + q];
        uint4 v0 = *(const uint4*)(p + (size_t)r0 * HID + g * 8);
        uint4 v1 = *(const uint4*)(p + (size_t)r1 * HID + g * 8);
        acc[0] += bf_lo(v0.x) + bf_lo(v1.x); acc[1] += bf_hi(v0.x) + bf_hi(v1.x);
        acc[2] += bf_lo(v0.y) + bf_lo(v1.y); acc[3] += bf_hi(v0.y) + bf_hi(v1.y);
        acc[4] += bf_lo(v0.z) + bf_lo(v1.z); acc[5] += bf_hi(v0.z) + bf_hi(v1.z);
        acc[6] += bf_lo(v0.w) + bf_lo(v1.w); acc[7] += bf_hi(v0.w) + bf_hi(v1.w);
    }
    for (; e < end; e += 8) {                   // masked tail
        int idx = e + q;
        int r = adj[min(idx, end - 1)];
        float m = (idx < end) ? 1.f : 0.f;
        uint4 v = *(const uint4*)(p + (size_t)r * HID + g * 8);
        acc[0] = fmaf(m, bf_lo(v.x), acc[0]); acc[1] = fmaf(m, bf_hi(v.x), acc[1]);
        acc[2] = fmaf(m, bf_lo(v.y), acc[2]); acc[3] = fmaf(m, bf_hi(v.y), acc[3]);
        acc[4] = fmaf(m, bf_lo(v.z), acc[4]); acc[5] = fmaf(m, bf_hi(v.z), acc[5]);
        acc[6] = fmaf(m, bf_lo(v.w), acc[6]); acc[7] = fmaf(m, bf_hi(v.w), acc[7]);
    }
#pragma unroll
    for (int j = 0; j < 8; ++j) {
        acc[j] += __shfl_xor(acc[j], 8, 64);
        acc[j] += __shfl_xor(acc[j], 16, 64);
        acc[j] += __shfl_xor(acc[j], 32, 64);
    }
    return (q & 4) ? ((q & 2) ? ((q & 1) ? acc[7] : acc[6]) : ((q & 1) ? acc[5] : acc[4]))
                   : ((q & 2) ? ((q & 1) ? acc[3] : acc[2]) : ((q & 1) ? acc[1] : acc[0]));
}

// ---------- gather1: h = relu(dis[c] * (p[c] + sum p[r]) + b1) ----------
__global__ __launch_bounds__(256) void gather1_kernel(const unsigned short* __restrict__ p,
                                                      const int* __restrict__ adj,
                                                      const int* __restrict__ offs,
                                                      const float* __restrict__ dis,
                                                      const float* __restrict__ b1,
                                                      float* __restrict__ h) {
    const int lane = threadIdx.x & 63;
    const int q = lane >> 3, g = lane & 7;
    const int gwave = (blockIdx.x * blockDim.x + threadIdx.x) >> 6;
    const int nwaves = (gridDim.x * blockDim.x) >> 6;
    const float bj = b1[g * 8 + q];
    for (int c = gwave; c < N_NODES; c += nwaves) {
        const int beg = offs[c], end = offs[c + 1];
        float val = gather_node(p, adj, c, beg, end, q, g);
        h[(size_t)c * HID + g * 8 + q] = fmaxf(dis[c] * val + bj, 0.f);
    }
}

// ---------- gather2 + fused mean-pool numerator ----------
__global__ __launch_bounds__(256) void gather2_kernel(const unsigned short* __restrict__ p,
                                                      const int* __restrict__ adj,
                                                      const int* __restrict__ offs,
                                                      const float* __restrict__ dis,
                                                      const float* __restrict__ b2,
                                                      const int* __restrict__ batch,
                                                      float* __restrict__ sums) {
    const int lane = threadIdx.x & 63;
    const int q = lane >> 3, g = lane & 7;
    const int gwave = (blockIdx.x * blockDim.x + threadIdx.x) >> 6;
    const int nwaves = (gridDim.x * blockDim.x) >> 6;
    const float bj = b2[g * 8 + q];
    for (int c = gwave; c < N_NODES; c += nwaves) {
        const int beg = offs[c], end = offs[c + 1];
        float val = gather_node(p, adj, c, beg, end, q, g);
        float v = fmaxf(dis[c] * val + bj, 0.f);
        atomicAdd(&sums[(size_t)batch[c] * HID + g * 8 + q], v);
    }
}

// ---------- final FC: out[g] = (sums[g]/max(count,1)) @ Wfc + bfc ----------
__global__ void fc_kernel(const float* __restrict__ sums, const int* __restrict__ counts,
                          const float* __restrict__ Wfc, const float* __restrict__ bfc,
                          float* __restrict__ out) {
    const int g = blockIdx.x;
    const int j = threadIdx.x;
    float cnt = fmaxf((float)counts[g], 1.0f);
    float pj = sums[(size_t)g * HID + j] / cnt;
    float a0 = pj * Wfc[j * N_CLASSES + 0];
    float a1 = pj * Wfc[j * N_CLASSES + 1];
    for (int off = 32; off > 0; off >>= 1) {
        a0 += __shfl_down(a0, off, 64);
        a1 += __shfl_down(a1, off, 64);
    }
    if (j == 0) {
        out[g * N_CLASSES + 0] = a0 + bfc[0];
        out[g * N_CLASSES + 1] = a1 + bfc[1];
    }
}

extern "C" void kernel_launch(void* const* d_in, const int* in_sizes, int n_in,
                              void* d_out, int out_size, void* d_ws, size_t ws_size,
                              hipStream_t stream) {
    const float* x     = (const float*)d_in[0];
    const int*   ei    = (const int*)d_in[1];   // [2,E]: row=ei[0:E], col=ei[E:2E]
    const int*   batch = (const int*)d_in[2];
    const float* W1    = (const float*)d_in[3];
    const float* b1    = (const float*)d_in[4];
    const float* W2    = (const float*)d_in[5];
    const float* b2    = (const float*)d_in[6];
    const float* Wfc   = (const float*)d_in[7];
    const float* bfc   = (const float*)d_in[8];
    float* out = (float*)d_out;

    char* ws = (char*)d_ws;
    size_t off = 0;
    auto alloc = [&](size_t bytes) -> void* {
        void* pp = ws + off;
        off += (bytes + 255) & ~(size_t)255;
        return pp;
    };
    int*   bcnt   = (int*)alloc((size_t)NB * 4);
    int*   boff   = (int*)alloc((size_t)(NB + 1) * 4);
    int*   gcur   = (int*)alloc((size_t)NB * 4);
    float* dis    = (float*)alloc((size_t)N_NODES * 4);
    int*   pairs  = (int*)alloc((size_t)N_EDGES * 4);
    int*   adj    = (int*)alloc((size_t)N_EDGES * 4);
    int*   offs   = (int*)alloc((size_t)(N_NODES + 1) * 4);
    unsigned short* p = (unsigned short*)alloc((size_t)N_NODES * HID * 2);
    float* h      = (float*)alloc((size_t)N_NODES * HID * 4);
    float* sums   = (float*)alloc((size_t)N_GRAPHS * HID * 4);
    int*   counts = (int*)alloc((size_t)N_GRAPHS * 4);

    hipMemsetAsync(bcnt, 0, (size_t)NB * 4, stream);
    hipMemsetAsync(sums, 0, (size_t)N_GRAPHS * HID * 4, stream);

    hist_kernel<<<SCAT_BLOCKS, 256, 0, stream>>>(ei, bcnt);
    scan_kernel<<<1, 1024, 0, stream>>>(bcnt, boff, gcur);
    scatter_kernel<<<SCAT_BLOCKS, 256, 0, stream>>>(ei, gcur, pairs);
    csr_kernel<<<NB, 256, 0, stream>>>(pairs, boff, adj, offs, dis);
    counts_kernel<<<2, 256, 0, stream>>>(batch, counts);
    mm1_kernel<<<(N_NODES + 63) / 64, 256, 0, stream>>>(x, W1, dis, p);
    gather1_kernel<<<2048, 256, 0, stream>>>(p, adj, offs, dis, b1, h);
    mm2_kernel<<<(N_NODES + 63) / 64, 256, 0, stream>>>(h, W2, dis, p);
    gather2_kernel<<<2048, 256, 0, stream>>>(p, adj, offs, dis, b2, batch, sums);
    fc_kernel<<<N_GRAPHS, 64, 0, stream>>>(sums, counts, Wfc, bfc, out);
}